// Round 1
// baseline (1473.028 us; speedup 1.0000x reference)
//
#include <hip/hip_runtime.h>

#define BB_ 8
#define NN_ 8192
#define SS_ 2048
#define NS 32
#define C1 64
#define C2 64
#define C3 128
#define RAD2 0.04f
#define BN_EPS 1e-5f
#define M_TOT (BB_*SS_*NS)   // 524288

// ws layout (float offsets)
#define CENT_OFF 0              // B*S*3 = 49152
#define FEAT_OFF 49152          // M_TOT*6 = 3145728
#define STAT_OFF 3194880        // 512: sum1[64] sq1[64] sum2[64] sq2[64] sum3[128] sq3[128]
#define AFF_OFF  3195392        // 512: a1 c1 a2 c2 (64 ea) a3 c3 (128 ea)
#define W3T_OFF  3195904        // 8192

// ---------------- ball query + centers + feat0 ----------------
__global__ void k_ballquery(const float* __restrict__ xyz, const float* __restrict__ pts,
                            const int* __restrict__ fps, float* __restrict__ centers,
                            float* __restrict__ feat0, float* __restrict__ out_xyz) {
    __shared__ int lidx[4][NS];
    int wave = (blockIdx.x * blockDim.x + threadIdx.x) >> 6;   // one wave per query
    int lane = threadIdx.x & 63;
    int wslot = threadIdx.x >> 6;
    int b = wave / SS_, s = wave - b * SS_;
    const float* xb = xyz + (size_t)b * 3 * NN_;
    const float* pb = pts + (size_t)b * 3 * NN_;
    int ci = fps[wave];
    float cx = xb[ci], cy = xb[NN_ + ci], cz = xb[2 * NN_ + ci];

    int found = 0;
    int first_i = -1;
    for (int base = 0; base < NN_; base += 64) {
        int i = base + lane;
        float dx = xb[i] - cx, dy = xb[NN_ + i] - cy, dz = xb[2 * NN_ + i] - cz;
        // avoid fma-contraction drift vs numpy reference at the radius boundary
        float d2 = __fadd_rn(__fadd_rn(__fmul_rn(dx, dx), __fmul_rn(dy, dy)), __fmul_rn(dz, dz));
        bool inr = d2 <= RAD2;
        unsigned long long mask = __ballot(inr);
        if (first_i < 0 && mask) first_i = base + __builtin_ctzll(mask);
        if (inr) {
            int pos = found + __popcll(mask & ((1ull << lane) - 1ull));
            if (pos < NS) lidx[wslot][pos] = i;
        }
        found += __popcll(mask);
        if (found >= NS) break;
    }
    if (found > NS) found = NS;
    __syncthreads();   // order LDS writes vs reads (cheap; all threads reach)

    if (lane < NS) {
        int j = (lane < found) ? lidx[wslot][lane] : first_i;
        size_t p = (size_t)wave * NS + lane;
        float* f = feat0 + p * 6;
        f[0] = xb[j] - cx; f[1] = xb[NN_ + j] - cy; f[2] = xb[2 * NN_ + j] - cz;
        f[3] = pb[j];      f[4] = pb[NN_ + j];      f[5] = pb[2 * NN_ + j];
    }
    if (lane == 0) {
        centers[wave * 3 + 0] = cx; centers[wave * 3 + 1] = cy; centers[wave * 3 + 2] = cz;
        out_xyz[((size_t)b * 3 + 0) * SS_ + s] = cx;
        out_xyz[((size_t)b * 3 + 1) * SS_ + s] = cy;
        out_xyz[((size_t)b * 3 + 2) * SS_ + s] = cz;
    }
}

// ---------------- transpose W3 [128,64] -> W3t [64,128] ----------------
__global__ void k_tw3(const float* __restrict__ W3, float* __restrict__ W3t) {
    int t = blockIdx.x * blockDim.x + threadIdx.x;
    if (t < C3 * C2) {
        int o3 = t / C2, o2 = t - o3 * C2;
        W3t[o2 * C3 + o3] = W3[o3 * C2 + o2];
    }
}

// ---------------- P1: stats of x1 ----------------
__global__ void k_p1(const float* __restrict__ feat0, const float* __restrict__ W1,
                     float* __restrict__ gsum, float* __restrict__ gsq) {
    __shared__ float lsum[4][C1], lsq[4][C1];
    int tid = threadIdx.x;
    int w = tid >> 6, lane = tid & 63;
    for (int i = tid; i < 4 * C1; i += blockDim.x) { (&lsum[0][0])[i] = 0.f; (&lsq[0][0])[i] = 0.f; }
    __syncthreads();
    int stride = gridDim.x * blockDim.x;
    for (int p = blockIdx.x * blockDim.x + tid; p < M_TOT; p += stride) {
        const float* fp = feat0 + (size_t)p * 6;
        float f[6];
        #pragma unroll
        for (int c = 0; c < 6; ++c) f[c] = fp[c];
        for (int o = 0; o < C1; ++o) {
            float v = 0.f;
            #pragma unroll
            for (int c = 0; c < 6; ++c) v = fmaf(f[c], W1[o * 6 + c], v);
            float v2 = v * v;
            #pragma unroll
            for (int d = 32; d; d >>= 1) { v += __shfl_xor(v, d); v2 += __shfl_xor(v2, d); }
            if (lane == 0) { lsum[w][o] += v; lsq[w][o] += v2; }
        }
    }
    __syncthreads();
    if (tid < C1) {
        atomicAdd(&gsum[tid], lsum[0][tid] + lsum[1][tid] + lsum[2][tid] + lsum[3][tid]);
        atomicAdd(&gsq[tid],  lsq[0][tid] + lsq[1][tid] + lsq[2][tid] + lsq[3][tid]);
    }
}

// ---------------- finalize: a = g*rsqrt(var+eps), c = b - m*a ----------------
__global__ void k_fin(const float* __restrict__ gsum, const float* __restrict__ gsq,
                      const float* __restrict__ g, const float* __restrict__ bb,
                      float* __restrict__ a, float* __restrict__ c, int C) {
    int t = threadIdx.x;
    if (t < C) {
        float m = gsum[t] / (float)M_TOT;
        float var = gsq[t] / (float)M_TOT - m * m;
        float ai = g[t] * (1.0f / sqrtf(var + BN_EPS));
        a[t] = ai;
        c[t] = bb[t] - m * ai;
    }
}

// ---------------- P2: y1 = relu(aff1(x1)); stats of x2 ----------------
__global__ void k_p2(const float* __restrict__ feat0, const float* __restrict__ W1,
                     const float* __restrict__ a1, const float* __restrict__ c1,
                     const float* __restrict__ W2,
                     float* __restrict__ gsum, float* __restrict__ gsq) {
    __shared__ float lsum[4][C2], lsq[4][C2];
    int tid = threadIdx.x;
    int w = tid >> 6, lane = tid & 63;
    for (int i = tid; i < 4 * C2; i += blockDim.x) { (&lsum[0][0])[i] = 0.f; (&lsq[0][0])[i] = 0.f; }
    __syncthreads();
    int stride = gridDim.x * blockDim.x;
    for (int p = blockIdx.x * blockDim.x + tid; p < M_TOT; p += stride) {
        const float* fp = feat0 + (size_t)p * 6;
        float f[6];
        #pragma unroll
        for (int c = 0; c < 6; ++c) f[c] = fp[c];
        float y1[C1];
        #pragma unroll
        for (int o = 0; o < C1; ++o) {
            float v = 0.f;
            #pragma unroll
            for (int c = 0; c < 6; ++c) v = fmaf(f[c], W1[o * 6 + c], v);
            y1[o] = fmaxf(fmaf(a1[o], v, c1[o]), 0.f);
        }
        for (int o2 = 0; o2 < C2; ++o2) {
            float v = 0.f;
            #pragma unroll
            for (int c = 0; c < C1; ++c) v = fmaf(y1[c], W2[o2 * C1 + c], v);
            float v2 = v * v;
            #pragma unroll
            for (int d = 32; d; d >>= 1) { v += __shfl_xor(v, d); v2 += __shfl_xor(v2, d); }
            if (lane == 0) { lsum[w][o2] += v; lsq[w][o2] += v2; }
        }
    }
    __syncthreads();
    if (tid < C2) {
        atomicAdd(&gsum[tid], lsum[0][tid] + lsum[1][tid] + lsum[2][tid] + lsum[3][tid]);
        atomicAdd(&gsq[tid],  lsq[0][tid] + lsq[1][tid] + lsq[2][tid] + lsq[3][tid]);
    }
}

// ---------------- P3: chain to x3, stats of x3 (acc3 in regs, W3 transposed) ----------------
__global__ __launch_bounds__(256, 2) void k_p3(
        const float* __restrict__ feat0, const float* __restrict__ W1,
        const float* __restrict__ a1, const float* __restrict__ c1,
        const float* __restrict__ W2, const float* __restrict__ a2, const float* __restrict__ c2,
        const float* __restrict__ W3t,
        float* __restrict__ gsum, float* __restrict__ gsq) {
    __shared__ float lsum[4][C3], lsq[4][C3];
    int tid = threadIdx.x;
    int w = tid >> 6, lane = tid & 63;
    for (int i = tid; i < 4 * C3; i += blockDim.x) { (&lsum[0][0])[i] = 0.f; (&lsq[0][0])[i] = 0.f; }
    __syncthreads();
    int stride = gridDim.x * blockDim.x;
    for (int p = blockIdx.x * blockDim.x + tid; p < M_TOT; p += stride) {
        const float* fp = feat0 + (size_t)p * 6;
        float f[6];
        #pragma unroll
        for (int c = 0; c < 6; ++c) f[c] = fp[c];
        float y1[C1];
        #pragma unroll
        for (int o = 0; o < C1; ++o) {
            float v = 0.f;
            #pragma unroll
            for (int c = 0; c < 6; ++c) v = fmaf(f[c], W1[o * 6 + c], v);
            y1[o] = fmaxf(fmaf(a1[o], v, c1[o]), 0.f);
        }
        float acc3[C3];
        #pragma unroll
        for (int o3 = 0; o3 < C3; ++o3) acc3[o3] = 0.f;
        for (int o2 = 0; o2 < C2; ++o2) {
            float v = 0.f;
            #pragma unroll
            for (int c = 0; c < C1; ++c) v = fmaf(y1[c], W2[o2 * C1 + c], v);
            float v2 = fmaxf(fmaf(a2[o2], v, c2[o2]), 0.f);
            #pragma unroll
            for (int o3 = 0; o3 < C3; ++o3) acc3[o3] = fmaf(v2, W3t[o2 * C3 + o3], acc3[o3]);
        }
        #pragma unroll
        for (int o3 = 0; o3 < C3; ++o3) {
            float v = acc3[o3], v2 = v * v;
            #pragma unroll
            for (int d = 32; d; d >>= 1) { v += __shfl_xor(v, d); v2 += __shfl_xor(v2, d); }
            if (lane == 0) { lsum[w][o3] += v; lsq[w][o3] += v2; }
        }
    }
    __syncthreads();
    if (tid < C3) {
        atomicAdd(&gsum[tid], lsum[0][tid] + lsum[1][tid] + lsum[2][tid] + lsum[3][tid]);
        atomicAdd(&gsq[tid],  lsq[0][tid] + lsq[1][tid] + lsq[2][tid] + lsq[3][tid]);
    }
}

// ---------------- P4: recompute chain -> y2 in LDS -> x3 -> relu(aff3) -> max_j ----------------
__global__ __launch_bounds__(128) void k_p4(
        const float* __restrict__ feat0, const float* __restrict__ W1,
        const float* __restrict__ a1, const float* __restrict__ c1,
        const float* __restrict__ W2, const float* __restrict__ a2, const float* __restrict__ c2,
        const float* __restrict__ W3, const float* __restrict__ a3, const float* __restrict__ c3,
        float* __restrict__ out_pts) {
    __shared__ float Y[4 * 32][68];   // 4 groups x 32 neighbors, +4 pad (16B-aligned rows)
    int t = threadIdx.x;
    {
        int gl = t >> 5, j = t & 31;
        size_t g = (size_t)blockIdx.x * 4 + gl;
        const float* fp = feat0 + (g * NS + j) * 6;
        float f[6];
        #pragma unroll
        for (int c = 0; c < 6; ++c) f[c] = fp[c];
        float y1[C1];
        #pragma unroll
        for (int o = 0; o < C1; ++o) {
            float v = 0.f;
            #pragma unroll
            for (int c = 0; c < 6; ++c) v = fmaf(f[c], W1[o * 6 + c], v);
            y1[o] = fmaxf(fmaf(a1[o], v, c1[o]), 0.f);
        }
        for (int o2 = 0; o2 < C2; ++o2) {
            float v = 0.f;
            #pragma unroll
            for (int c = 0; c < C1; ++c) v = fmaf(y1[c], W2[o2 * C1 + c], v);
            Y[gl * 32 + j][o2] = fmaxf(fmaf(a2[o2], v, c2[o2]), 0.f);
        }
    }
    __syncthreads();
    int w = t >> 6, lane = t & 63;
    for (int gg = 0; gg < 2; ++gg) {
        int gl = w * 2 + gg;
        int g = blockIdx.x * 4 + gl;
        int b = g >> 11, s = g & (SS_ - 1);
        for (int half = 0; half < 2; ++half) {
            int o = half * 64 + lane;
            float w3r[C2];
            #pragma unroll
            for (int c = 0; c < C2; ++c) w3r[c] = W3[o * C2 + c];
            float aa = a3[o], cc = c3[o];
            float mv = 0.f;   // relu >= 0 so max >= 0
            for (int j = 0; j < NS; ++j) {
                const float* yr = &Y[gl * 32 + j][0];
                float sacc = 0.f;
                #pragma unroll
                for (int c = 0; c < C2; ++c) sacc = fmaf(yr[c], w3r[c], sacc);
                mv = fmaxf(mv, fmaxf(fmaf(aa, sacc, cc), 0.f));
            }
            out_pts[((size_t)b * C3 + o) * SS_ + s] = mv;
        }
    }
}

extern "C" void kernel_launch(void* const* d_in, const int* in_sizes, int n_in,
                              void* d_out, int out_size, void* d_ws, size_t ws_size,
                              hipStream_t stream) {
    (void)in_sizes; (void)n_in; (void)out_size; (void)ws_size;
    const float* xyz = (const float*)d_in[0];
    const float* pts = (const float*)d_in[1];
    const int*   fps = (const int*)d_in[2];
    const float* W1 = (const float*)d_in[3];
    const float* g1 = (const float*)d_in[4];
    const float* b1 = (const float*)d_in[5];
    const float* W2 = (const float*)d_in[6];
    const float* g2 = (const float*)d_in[7];
    const float* b2 = (const float*)d_in[8];
    const float* W3 = (const float*)d_in[9];
    const float* g3 = (const float*)d_in[10];
    const float* b3 = (const float*)d_in[11];
    float* out = (float*)d_out;
    float* ws = (float*)d_ws;

    float* centers = ws + CENT_OFF;
    float* feat0   = ws + FEAT_OFF;
    float* st      = ws + STAT_OFF;
    float* sum1 = st,       *sq1 = st + 64;
    float* sum2 = st + 128, *sq2 = st + 192;
    float* sum3 = st + 256, *sq3 = st + 384;
    float* af = ws + AFF_OFF;
    float* a1 = af,       *c1 = af + 64;
    float* a2 = af + 128, *c2 = af + 192;
    float* a3 = af + 256, *c3 = af + 384;
    float* W3t = ws + W3T_OFF;

    hipMemsetAsync(st, 0, 512 * sizeof(float), stream);
    k_tw3<<<(C3 * C2 + 255) / 256, 256, 0, stream>>>(W3, W3t);
    k_ballquery<<<(BB_ * SS_) / 4, 256, 0, stream>>>(xyz, pts, fps, centers, feat0, out);
    k_p1<<<512, 256, 0, stream>>>(feat0, W1, sum1, sq1);
    k_fin<<<1, 128, 0, stream>>>(sum1, sq1, g1, b1, a1, c1, C1);
    k_p2<<<512, 256, 0, stream>>>(feat0, W1, a1, c1, W2, sum2, sq2);
    k_fin<<<1, 128, 0, stream>>>(sum2, sq2, g2, b2, a2, c2, C2);
    k_p3<<<512, 256, 0, stream>>>(feat0, W1, a1, c1, W2, a2, c2, W3t, sum3, sq3);
    k_fin<<<1, 128, 0, stream>>>(sum3, sq3, g3, b3, a3, c3, C3);
    k_p4<<<(BB_ * SS_) / 4, 128, 0, stream>>>(feat0, W1, a1, c1, W2, a2, c2, W3, a3, c3,
                                              out + (size_t)BB_ * 3 * SS_);
}